// Round 1
// baseline (574.569 us; speedup 1.0000x reference)
//
#include <hip/hip_runtime.h>

#define TSTEPS 256
#define HID 50
#define NQ 4

__device__ __forceinline__ float bcast(float v, int l) {
    return __int_as_float(__builtin_amdgcn_readlane(__float_as_int(v), l));
}
__device__ __forceinline__ float fast_sigmoid(float x) {
    float e = __expf(-x);
    return __builtin_amdgcn_rcpf(1.0f + e);
}
__device__ __forceinline__ float fast_tanh(float x) {
    // 1 - 2/(1+e^{2x}); saturates correctly at +-inf
    float e = __expf(2.0f * x);
    return 1.0f - 2.0f * __builtin_amdgcn_rcpf(1.0f + e);
}

__global__ __launch_bounds__(64, 2) void hybrid_lstm_q(
    const float* __restrict__ x,      // [B,256,1]
    const float* __restrict__ W_ih,   // [200,1]
    const float* __restrict__ W_hh,   // [200,50]
    const float* __restrict__ b_ih,   // [200]
    const float* __restrict__ b_hh,   // [200]
    const float* __restrict__ Wp,     // [4,50]
    const float* __restrict__ bp,     // [4]
    const float* __restrict__ qw,     // [2,4,3]
    const float* __restrict__ Wo,     // [1,4]
    const float* __restrict__ bo,     // [1]
    float* __restrict__ out)          // [B,1]
{
    const int b = blockIdx.x;
    const int lane = threadIdx.x & 63;
    const int j = lane < HID ? lane : 0;  // hidden unit owned by this lane

    // Lane j holds gate rows {j, j+50, j+100, j+150} = (i,f,g,o) of unit j.
    float w[4][HID], wih[4], bsum[4];
#pragma unroll
    for (int q = 0; q < 4; ++q) {
        const int g = j + q * HID;
        wih[q]  = W_ih[g];
        bsum[q] = b_ih[g] + b_hh[g];
#pragma unroll
        for (int k = 0; k < HID; ++k) w[q][k] = W_hh[g * HID + k];
    }

    const float* xb = x + (size_t)b * TSTEPS;
    float h = 0.0f, c = 0.0f;

#pragma unroll 1
    for (int t0 = 0; t0 < TSTEPS; t0 += 64) {
        const float xreg = xb[t0 + lane];  // 64 timesteps staged per chunk
#pragma unroll 1
        for (int tt = 0; tt < 64; ++tt) {
            const float xt = bcast(xreg, tt);  // uniform lane index -> SGPR
            float a0 = fmaf(xt, wih[0], bsum[0]);
            float a1 = fmaf(xt, wih[1], bsum[1]);
            float a2 = fmaf(xt, wih[2], bsum[2]);
            float a3 = fmaf(xt, wih[3], bsum[3]);
#pragma unroll
            for (int k = 0; k < HID; ++k) {
                const float hk = bcast(h, k);  // broadcast h_k via readlane
                a0 = fmaf(w[0][k], hk, a0);
                a1 = fmaf(w[1][k], hk, a1);
                a2 = fmaf(w[2][k], hk, a2);
                a3 = fmaf(w[3][k], hk, a3);
            }
            const float ig = fast_sigmoid(a0);
            const float fg = fast_sigmoid(a1);
            const float gg = fast_tanh(a2);
            const float og = fast_sigmoid(a3);
            c = fmaf(fg, c, ig * gg);
            h = og * fast_tanh(c);
        }
    }

    // angles = tanh(h @ Wp.T + bp) * pi/2 — computed redundantly on all lanes
    float ang[NQ];
#pragma unroll
    for (int q = 0; q < NQ; ++q) ang[q] = bp[q];
#pragma unroll
    for (int k = 0; k < HID; ++k) {
        const float hk = bcast(h, k);
#pragma unroll
        for (int q = 0; q < NQ; ++q)
            ang[q] = fmaf(Wp[q * HID + k], hk, ang[q]);
    }
#pragma unroll
    for (int q = 0; q < NQ; ++q)
        ang[q] = fast_tanh(ang[q]) * 1.57079632679489662f;

    // ---- 4-qubit statevector: lane a (a<16) holds amplitude of |a>,
    // wire w <-> bit (8>>w) (state tensor axis order). ----
    float ar = (lane == 0) ? 1.0f : 0.0f;
    float ai = 0.0f;

    // RX embedding: U = [[c, -i s], [-i s, c]]
#pragma unroll
    for (int wq = 0; wq < NQ; ++wq) {
        const int mask = 8 >> wq;
        float s_, c_;
        __sincosf(0.5f * ang[wq], &s_, &c_);
        const float pr = __shfl_xor(ar, mask);
        const float pi = __shfl_xor(ai, mask);
        const float nr = c_ * ar + s_ * pi;
        const float ni = c_ * ai - s_ * pr;
        ar = nr; ai = ni;
    }

    // StronglyEntanglingLayers: Rot(phi,th,om) per wire, then CNOT ring
#pragma unroll
    for (int l = 0; l < 2; ++l) {
#pragma unroll
        for (int wq = 0; wq < NQ; ++wq) {
            const float phi = qw[(l * NQ + wq) * 3 + 0];
            const float th  = qw[(l * NQ + wq) * 3 + 1];
            const float om  = qw[(l * NQ + wq) * 3 + 2];
            float st_, ct_, sa, ca, sb, cb;
            __sincosf(0.5f * th, &st_, &ct_);
            __sincosf(0.5f * (phi + om), &sa, &ca);
            __sincosf(0.5f * (phi - om), &sb, &cb);
            const int mask = 8 >> wq;
            const bool bit = (lane & mask) != 0;
            // bit==0: new = U00*a + U01*p ; bit==1: new = U11*a + U10*p
            const float dr  = ca * ct_;
            const float di  = (bit ? sa : -sa) * ct_;
            const float orr = (bit ? cb : -cb) * st_;
            const float oi  = -sb * st_;
            const float pr = __shfl_xor(ar, mask);
            const float pi = __shfl_xor(ai, mask);
            const float nr = dr * ar - di * ai + orr * pr - oi * pi;
            const float ni = dr * ai + di * ar + orr * pi + oi * pr;
            ar = nr; ai = ni;
        }
        const int r = (l % (NQ - 1)) + 1;
#pragma unroll
        for (int wq = 0; wq < NQ; ++wq) {
            const int mc  = 8 >> wq;
            const int mt  = 8 >> ((wq + r) % NQ);
            const int src = (lane & mc) ? (lane ^ mt) : lane;  // pull permutation
            ar = __shfl(ar, src);
            ai = __shfl(ai, src);
        }
    }

    // <Z_w> folded with Wo: out = sum_a |amp_a|^2 * sum_w sign_w(a)*Wo[w] + bo
    const float prob = (lane < 16) ? (ar * ar + ai * ai) : 0.0f;
    float coeff = 0.0f;
#pragma unroll
    for (int wq = 0; wq < NQ; ++wq) {
        const float sgn = (lane & (8 >> wq)) ? -1.0f : 1.0f;
        coeff = fmaf(sgn, Wo[wq], coeff);
    }
    float v = prob * coeff;
    v += __shfl_xor(v, 1);
    v += __shfl_xor(v, 2);
    v += __shfl_xor(v, 4);
    v += __shfl_xor(v, 8);
    if (lane == 0) out[b] = v + bo[0];
}

extern "C" void kernel_launch(void* const* d_in, const int* in_sizes, int n_in,
                              void* d_out, int out_size, void* d_ws, size_t ws_size,
                              hipStream_t stream) {
    const float* x    = (const float*)d_in[0];
    const float* W_ih = (const float*)d_in[1];
    const float* W_hh = (const float*)d_in[2];
    const float* b_ih = (const float*)d_in[3];
    const float* b_hh = (const float*)d_in[4];
    const float* Wp   = (const float*)d_in[5];
    const float* bp   = (const float*)d_in[6];
    const float* qw   = (const float*)d_in[7];
    const float* Wo   = (const float*)d_in[8];
    const float* bo   = (const float*)d_in[9];
    float* out = (float*)d_out;

    const int B = in_sizes[0] / TSTEPS;  // x is [B,256,1]
    hybrid_lstm_q<<<B, 64, 0, stream>>>(x, W_ih, W_hh, b_ih, b_hh,
                                        Wp, bp, qw, Wo, bo, out);
}

// Round 2
// 191.335 us; speedup vs baseline: 3.0029x; 3.0029x over previous
//
#include <hip/hip_runtime.h>

#define HID 50
#define TSTEPS 256
#define SPB 16           // samples per block (MFMA N)
#define NWAVE 8
#define HSTRIDE 136      // shorts per sample in h_lds (272B, 16B-aligned, bank-tiled)
#define XSTRIDE 257      // floats per sample in x_lds (bank-spread)

typedef __attribute__((ext_vector_type(8))) short short8;
typedef __attribute__((ext_vector_type(4))) float f32x4;

static __device__ __forceinline__ f32x4 MF(short8 a, short8 b, f32x4 c) {
    return __builtin_amdgcn_mfma_f32_16x16x32_bf16(a, b, c, 0, 0, 0);
}
static __device__ __forceinline__ unsigned short f2bf(float f) {   // RTNE
    unsigned u = __float_as_uint(f);
    return (unsigned short)((u + 0x7FFFu + ((u >> 16) & 1u)) >> 16);
}
static __device__ __forceinline__ float bf2f(unsigned short b) {
    return __uint_as_float(((unsigned)b) << 16);
}
static __device__ __forceinline__ float fast_sigmoid(float x) {
    float e = __expf(-x);
    return __builtin_amdgcn_rcpf(1.0f + e);
}
static __device__ __forceinline__ float fast_tanh(float x) {
    float e = __expf(2.0f * x);
    return 1.0f - 2.0f * __builtin_amdgcn_rcpf(1.0f + e);
}

__global__ __launch_bounds__(512, 2) void hybrid_lstm_mfma(
    const float* __restrict__ x,      // [B,256,1]
    const float* __restrict__ W_ih,   // [200,1]
    const float* __restrict__ W_hh,   // [200,50]
    const float* __restrict__ b_ih,   // [200]
    const float* __restrict__ b_hh,   // [200]
    const float* __restrict__ Wp,     // [4,50]
    const float* __restrict__ bp,     // [4]
    const float* __restrict__ qw,     // [2,4,3]
    const float* __restrict__ Wo,     // [1,4]
    const float* __restrict__ bo,     // [1]
    float* __restrict__ out)          // [B,1]
{
    __shared__ float x_lds[SPB * XSTRIDE];                 // [s][t]
    __shared__ unsigned short h_lds[2][SPB * HSTRIDE];     // hi at [s*136+u], lo at +64

    const int tid  = threadIdx.x;
    const int wid  = tid >> 6;
    const int lane = tid & 63;
    const int qs   = lane & 15;   // sample (N) / row-within-tile selector
    const int g2   = lane >> 4;   // K-group / row-group selector
    const int sB   = qs * HSTRIDE;

    // ---------- prologue: zero h buffers, stage x ----------
    {
        unsigned* hz = (unsigned*)&h_lds[0][0];
        for (int i = tid; i < 2 * SPB * HSTRIDE / 2; i += 512) hz[i] = 0u;
        const float* xg = x + (size_t)blockIdx.x * SPB * TSTEPS;
        for (int i = tid; i < SPB * TSTEPS; i += 512) {
            int s = i >> 8, t = i & 255;
            x_lds[s * XSTRIDE + t] = xg[i];
        }
    }

    // ---------- build A fragments (weights, gate-interleaved rows, hi/lo split) ----------
    // row' = 4*unit + gate (gate order i,f,g,o).  k: 0..49 = h, 50 = x, 51 = 1(bias), rest 0.
    short8 Ahi[2][2], Alo[2][2];
#pragma unroll
    for (int ti = 0; ti < 2; ++ti) {
        const int tile = 2 * wid + ti;
        const int row  = tile * 16 + qs;
        const int ur   = row >> 2;
        const int q    = row & 3;
        const bool vr  = (row < 200);
        const int gr   = q * HID + ur;    // original gate-row index
#pragma unroll
        for (int kh = 0; kh < 2; ++kh) {
#pragma unroll
            for (int r = 0; r < 8; ++r) {
                const int k = kh * 32 + g2 * 8 + r;
                float v = 0.0f;
                if (vr) {
                    if (k < HID)      v = W_hh[gr * HID + k];
                    else if (k == 50) v = W_ih[gr];
                    else if (k == 51) v = b_ih[gr] + b_hh[gr];
                }
                const unsigned short hi = f2bf(v);
                const unsigned short lo = f2bf(v - bf2f(hi));
                Ahi[ti][kh][r] = (short)hi;
                Alo[ti][kh][r] = (short)lo;
            }
        }
    }

    __syncthreads();

    // units owned by this lane: tile0=2w -> u0, tile1=2w+1 -> u1
    const int u0 = 8 * wid + g2;
    const int u1 = u0 + 4;
    float c0 = 0.0f, c1 = 0.0f;

    short8 bh0, bh1, bl0, bl1;
    // build B for step t from buffer `buf` (h(t-1)) and x_t
    auto loadB = [&](int buf, int t) {
        const unsigned short* hb = &h_lds[buf][0];
        const int base = sB + g2 * 8;
        bh0 = *(const short8*)(hb + base);
        bh1 = *(const short8*)(hb + base + 32);
        bl0 = *(const short8*)(hb + base + 64);
        bl1 = *(const short8*)(hb + base + 96);
        const float xv = x_lds[qs * XSTRIDE + t];
        const unsigned short xh = f2bf(xv);
        const unsigned short xl = f2bf(xv - bf2f(xh));
        if (g2 == 2) {            // k=50,51 live in this K-group, elements 2,3
            bh1[2] = (short)xh; bh1[3] = (short)0x3F80;   // bf16(1.0)
            bl1[2] = (short)xl; bl1[3] = 0;
        }
    };

    loadB(1, 0);   // h(-1)=0 from zeroed buf1

#pragma unroll 2
    for (int t = 0; t < TSTEPS; ++t) {
        // 3-term split product: Ahi*Bhi + Ahi*Blo + Alo*Bhi  (per tile, K=64 in 2 chunks)
        f32x4 acc0 = {0.f, 0.f, 0.f, 0.f};
        f32x4 acc1 = {0.f, 0.f, 0.f, 0.f};
        acc0 = MF(Ahi[0][0], bh0, acc0); acc0 = MF(Ahi[0][1], bh1, acc0);
        acc1 = MF(Ahi[1][0], bh0, acc1); acc1 = MF(Ahi[1][1], bh1, acc1);
        acc0 = MF(Ahi[0][0], bl0, acc0); acc0 = MF(Ahi[0][1], bl1, acc0);
        acc1 = MF(Ahi[1][0], bl0, acc1); acc1 = MF(Ahi[1][1], bl1, acc1);
        acc0 = MF(Alo[0][0], bh0, acc0); acc0 = MF(Alo[0][1], bh1, acc0);
        acc1 = MF(Alo[1][0], bh0, acc1); acc1 = MF(Alo[1][1], bh1, acc1);

        // gates are lane-local: acc = (i,f,g,o) pre-activations for unit u0/u1, sample qs
        const float i0 = fast_sigmoid(acc0[0]);
        const float f0 = fast_sigmoid(acc0[1]);
        const float g0 = fast_tanh(acc0[2]);
        const float o0 = fast_sigmoid(acc0[3]);
        c0 = fmaf(f0, c0, i0 * g0);
        const float h0 = o0 * fast_tanh(c0);

        const float i1 = fast_sigmoid(acc1[0]);
        const float f1 = fast_sigmoid(acc1[1]);
        const float g1 = fast_tanh(acc1[2]);
        const float o1 = fast_sigmoid(acc1[3]);
        c1 = fmaf(f1, c1, i1 * g1);
        const float h1 = o1 * fast_tanh(c1);

        // write h(t) split to buf[t&1]
        unsigned short* hw = &h_lds[t & 1][0];
        if (u0 < HID) {
            const unsigned short hh = f2bf(h0);
            hw[sB + u0]      = hh;
            hw[sB + 64 + u0] = f2bf(h0 - bf2f(hh));
        }
        if (u1 < HID) {
            const unsigned short hh = f2bf(h1);
            hw[sB + u1]      = hh;
            hw[sB + 64 + u1] = f2bf(h1 - bf2f(hh));
        }
        __syncthreads();
        if (t < TSTEPS - 1) loadB(t & 1, t + 1);
    }

    // ---------- epilogue: angles + 4-qubit circuit, 2 samples per wave ----------
    if (lane < 32) {
        const int s  = 2 * wid + (lane >> 4);   // local sample
        const int ql = lane & 15;               // amplitude index |ql>
        const int grp = lane & 48;

        const unsigned short* hf = &h_lds[1][s * HSTRIDE];  // h(255) lives in buf1
        float ang0 = bp[0], ang1 = bp[1], ang2 = bp[2], ang3 = bp[3];
#pragma unroll
        for (int k = 0; k < HID; ++k) {
            const float hk = bf2f(hf[k]) + bf2f(hf[64 + k]);
            ang0 = fmaf(Wp[0 * HID + k], hk, ang0);
            ang1 = fmaf(Wp[1 * HID + k], hk, ang1);
            ang2 = fmaf(Wp[2 * HID + k], hk, ang2);
            ang3 = fmaf(Wp[3 * HID + k], hk, ang3);
        }
        float ang[4];
        ang[0] = fast_tanh(ang0) * 1.57079632679489662f;
        ang[1] = fast_tanh(ang1) * 1.57079632679489662f;
        ang[2] = fast_tanh(ang2) * 1.57079632679489662f;
        ang[3] = fast_tanh(ang3) * 1.57079632679489662f;

        float ar = (ql == 0) ? 1.0f : 0.0f;
        float ai = 0.0f;

        // RX embedding
#pragma unroll
        for (int wq = 0; wq < 4; ++wq) {
            const int mask = 8 >> wq;
            float s_, c_;
            __sincosf(0.5f * ang[wq], &s_, &c_);
            const float pr = __shfl_xor(ar, mask);
            const float pi = __shfl_xor(ai, mask);
            const float nr = c_ * ar + s_ * pi;
            const float ni = c_ * ai - s_ * pr;
            ar = nr; ai = ni;
        }
        // StronglyEntanglingLayers
#pragma unroll
        for (int l = 0; l < 2; ++l) {
#pragma unroll
            for (int wq = 0; wq < 4; ++wq) {
                const float phi = qw[(l * 4 + wq) * 3 + 0];
                const float th  = qw[(l * 4 + wq) * 3 + 1];
                const float om  = qw[(l * 4 + wq) * 3 + 2];
                float st_, ct_, sa, ca, sb, cb;
                __sincosf(0.5f * th, &st_, &ct_);
                __sincosf(0.5f * (phi + om), &sa, &ca);
                __sincosf(0.5f * (phi - om), &sb, &cb);
                const int mask = 8 >> wq;
                const bool bit = (ql & mask) != 0;
                const float dr  = ca * ct_;
                const float di  = (bit ? sa : -sa) * ct_;
                const float orr = (bit ? cb : -cb) * st_;
                const float oi  = -sb * st_;
                const float pr = __shfl_xor(ar, mask);
                const float pi = __shfl_xor(ai, mask);
                const float nr = dr * ar - di * ai + orr * pr - oi * pi;
                const float ni = dr * ai + di * ar + orr * pi + oi * pr;
                ar = nr; ai = ni;
            }
            const int r = (l % 3) + 1;
#pragma unroll
            for (int wq = 0; wq < 4; ++wq) {
                const int mc  = 8 >> wq;
                const int mt  = 8 >> ((wq + r) % 4);
                const int src = (ql & mc) ? (ql ^ mt) : ql;
                ar = __shfl(ar, grp | src);
                ai = __shfl(ai, grp | src);
            }
        }
        const float prob = ar * ar + ai * ai;
        float coeff = 0.0f;
#pragma unroll
        for (int wq = 0; wq < 4; ++wq) {
            const float sgn = (ql & (8 >> wq)) ? -1.0f : 1.0f;
            coeff = fmaf(sgn, Wo[wq], coeff);
        }
        float v = prob * coeff;
        v += __shfl_xor(v, 1);
        v += __shfl_xor(v, 2);
        v += __shfl_xor(v, 4);
        v += __shfl_xor(v, 8);
        if (ql == 0) out[blockIdx.x * SPB + s] = v + bo[0];
    }
}

extern "C" void kernel_launch(void* const* d_in, const int* in_sizes, int n_in,
                              void* d_out, int out_size, void* d_ws, size_t ws_size,
                              hipStream_t stream) {
    const float* x    = (const float*)d_in[0];
    const float* W_ih = (const float*)d_in[1];
    const float* W_hh = (const float*)d_in[2];
    const float* b_ih = (const float*)d_in[3];
    const float* b_hh = (const float*)d_in[4];
    const float* Wp   = (const float*)d_in[5];
    const float* bp   = (const float*)d_in[6];
    const float* qw   = (const float*)d_in[7];
    const float* Wo   = (const float*)d_in[8];
    const float* bo   = (const float*)d_in[9];
    float* out = (float*)d_out;

    const int B = in_sizes[0] / TSTEPS;
    hybrid_lstm_mfma<<<B / SPB, 512, 0, stream>>>(x, W_ih, W_hh, b_ih, b_hh,
                                                  Wp, bp, qw, Wo, bo, out);
}

// Round 3
// 152.260 us; speedup vs baseline: 3.7736x; 1.2566x over previous
//
#include <hip/hip_runtime.h>

#define HID 50
#define TSTEPS 256
#define SPB 16              // samples per block (MFMA N)
#define NW 13               // waves per block, 1 M-tile (16 rows) each: 13*16 = 208 rows
#define THREADS (NW * 64)
#define HSTRIDE 136         // shorts per sample: [0..63] hi slots, [64..127] lo slots, pad
#define XSTRIDE 257         // floats per sample in x_lds

typedef __attribute__((ext_vector_type(8))) short short8;
typedef __attribute__((ext_vector_type(4))) float f32x4;

static __device__ __forceinline__ f32x4 MF(short8 a, short8 b, f32x4 c) {
    return __builtin_amdgcn_mfma_f32_16x16x32_bf16(a, b, c, 0, 0, 0);
}
static __device__ __forceinline__ unsigned short f2bf(float f) {   // RTNE
    unsigned u = __float_as_uint(f);
    return (unsigned short)((u + 0x7FFFu + ((u >> 16) & 1u)) >> 16);
}
static __device__ __forceinline__ float bf2f(unsigned short b) {
    return __uint_as_float(((unsigned)b) << 16);
}
static __device__ __forceinline__ float fast_sigmoid(float x) {
    float e = __expf(-x);
    return __builtin_amdgcn_rcpf(1.0f + e);
}
static __device__ __forceinline__ float fast_tanh(float x) {
    float e = __expf(2.0f * x);
    return 1.0f - 2.0f * __builtin_amdgcn_rcpf(1.0f + e);
}

__global__ __launch_bounds__(THREADS, 4) void hybrid_lstm_mfma13(
    const float* __restrict__ x,      // [B,256,1]
    const float* __restrict__ W_ih,   // [200,1]
    const float* __restrict__ W_hh,   // [200,50]
    const float* __restrict__ b_ih,   // [200]
    const float* __restrict__ b_hh,   // [200]
    const float* __restrict__ Wp,     // [4,50]
    const float* __restrict__ bp,     // [4]
    const float* __restrict__ qw,     // [2,4,3]
    const float* __restrict__ Wo,     // [1,4]
    const float* __restrict__ bo,     // [1]
    float* __restrict__ out)          // [B,1]
{
    __shared__ __align__(16) float x_lds[SPB * XSTRIDE];
    __shared__ __align__(16) unsigned short h_lds[2][SPB * HSTRIDE];

    const int tid  = threadIdx.x;
    const int wid  = tid >> 6;        // tile index 0..12
    const int lane = tid & 63;
    const int qs   = lane & 15;       // sample / A-row-within-tile
    const int g2   = lane >> 4;       // K-group / C-row-group

    // ---------- prologue: zero h buffers, stage x ----------
    {
        unsigned* hz = (unsigned*)&h_lds[0][0];
        for (int i = tid; i < 2 * SPB * HSTRIDE / 2; i += THREADS) hz[i] = 0u;
        const float* xg = x + (size_t)blockIdx.x * SPB * TSTEPS;
        for (int i = tid; i < SPB * TSTEPS; i += THREADS)
            x_lds[(i >> 8) * XSTRIDE + (i & 255)] = xg[i];
    }

    // ---------- A fragments ----------
    // A-row (load view): row' = 16*wid + qs -> unit uA = 4*wid + (qs>>2), gate = qs&3
    // orig gate-row = gate*HID + uA  (gate order i,f,g,o)
    // K slot s holds h of unit un(s) = 4*(s%13) + s/13  (write permutation sigma)
    short8 Ahi[2], Alo[2];
    {
        const int uA   = 4 * wid + (qs >> 2);
        const bool vr  = (uA < HID);
        const int orow = (qs & 3) * HID + (vr ? uA : 0);
#pragma unroll
        for (int kh = 0; kh < 2; ++kh) {
#pragma unroll
            for (int r = 0; r < 8; ++r) {
                const int s = kh * 32 + g2 * 8 + r;
                float v = 0.0f;
                if (vr && s < 52) {
                    const int un = 4 * (s % 13) + s / 13;
                    if (un < HID) v = W_hh[orow * HID + un];
                }
                const unsigned short hi = f2bf(v);
                Ahi[kh][r] = (short)hi;
                Alo[kh][r] = (short)f2bf(v - bf2f(hi));
            }
        }
    }

    // per-lane gate constants: this lane owns unit u = 4*wid + g2 for sample qs
    const int u   = 4 * wid + g2;
    const bool uv = (u < HID);
    const int sig = 13 * g2 + wid;    // storage slot for unit u
    float wih4[4], bsum4[4];
#pragma unroll
    for (int reg = 0; reg < 4; ++reg) {
        const int orow = reg * HID + (uv ? u : 0);
        wih4[reg]  = W_ih[orow];
        bsum4[reg] = b_ih[orow] + b_hh[orow];
    }

    __syncthreads();

    float cst = 0.0f;
    short8 bh0, bh1, bl0, bl1;
    float xt;
    const unsigned short* __restrict__ hbase = &h_lds[0][0];
    unsigned short* __restrict__ hwbase = &h_lds[0][0];

    // load B fragment (h(t-1)) from buffer buf, and x_t
    auto loadB = [&](int buf, int t) {
        const unsigned short* hb = hbase + buf * (SPB * HSTRIDE) + qs * HSTRIDE + g2 * 8;
        bh0 = *(const short8*)(hb);
        bh1 = *(const short8*)(hb + 32);
        bl0 = *(const short8*)(hb + 64);
        bl1 = *(const short8*)(hb + 96);
        xt  = x_lds[qs * XSTRIDE + t];
    };

    loadB(1, 0);   // h(-1) = 0 from zeroed buf1

#pragma unroll 2
    for (int t = 0; t < TSTEPS; ++t) {
        // acc init carries exact fp32 bias + W_ih*x_t
        f32x4 accA, accB;
#pragma unroll
        for (int reg = 0; reg < 4; ++reg) {
            accA[reg] = fmaf(wih4[reg], xt, bsum4[reg]);
            accB[reg] = 0.0f;
        }
        // 3-term split product as two independent 3-chains
        accA = MF(Ahi[0], bh0, accA);
        accB = MF(Ahi[0], bl0, accB);
        accA = MF(Ahi[1], bh1, accA);
        accB = MF(Ahi[1], bl1, accB);
        accA = MF(Alo[0], bh0, accA);
        accB = MF(Alo[1], bh1, accB);

        const float a0 = accA[0] + accB[0];
        const float a1 = accA[1] + accB[1];
        const float a2 = accA[2] + accB[2];
        const float a3 = accA[3] + accB[3];

        const float ig = fast_sigmoid(a0);
        const float fg = fast_sigmoid(a1);
        const float gg = fast_tanh(a2);
        const float og = fast_sigmoid(a3);
        cst = fmaf(fg, cst, ig * gg);
        const float h = og * fast_tanh(cst);

        if (uv) {
            const unsigned short hh = f2bf(h);
            unsigned short* hw = hwbase + (t & 1) * (SPB * HSTRIDE) + qs * HSTRIDE;
            hw[sig]      = hh;
            hw[64 + sig] = f2bf(h - bf2f(hh));
        }
        __syncthreads();
        loadB(t & 1, t + 1);   // t=255 reads x_lds[...+256] (in-bounds, unused)
    }

    // ---------- epilogue: angles + 4-qubit circuit, 2 samples per wave (waves 0-7) ----------
    if (wid < 8 && lane < 32) {
        const int s   = 2 * wid + (lane >> 4);
        const int ql  = lane & 15;
        const int grp = lane & 48;

        const unsigned short* hf = &h_lds[1][s * HSTRIDE];  // h(255) lives in buf1
        float ang0 = bp[0], ang1 = bp[1], ang2 = bp[2], ang3 = bp[3];
#pragma unroll
        for (int k = 0; k < HID; ++k) {
            const int sl = 13 * (k & 3) + (k >> 2);         // sigma(k)
            const float hk = bf2f(hf[sl]) + bf2f(hf[64 + sl]);
            ang0 = fmaf(Wp[0 * HID + k], hk, ang0);
            ang1 = fmaf(Wp[1 * HID + k], hk, ang1);
            ang2 = fmaf(Wp[2 * HID + k], hk, ang2);
            ang3 = fmaf(Wp[3 * HID + k], hk, ang3);
        }
        float ang[4];
        ang[0] = fast_tanh(ang0) * 1.57079632679489662f;
        ang[1] = fast_tanh(ang1) * 1.57079632679489662f;
        ang[2] = fast_tanh(ang2) * 1.57079632679489662f;
        ang[3] = fast_tanh(ang3) * 1.57079632679489662f;

        float ar = (ql == 0) ? 1.0f : 0.0f;
        float ai = 0.0f;

        // RX embedding
#pragma unroll
        for (int wq = 0; wq < 4; ++wq) {
            const int mask = 8 >> wq;
            float s_, c_;
            __sincosf(0.5f * ang[wq], &s_, &c_);
            const float pr = __shfl_xor(ar, mask);
            const float pi = __shfl_xor(ai, mask);
            const float nr = c_ * ar + s_ * pi;
            const float ni = c_ * ai - s_ * pr;
            ar = nr; ai = ni;
        }
        // StronglyEntanglingLayers
#pragma unroll
        for (int l = 0; l < 2; ++l) {
#pragma unroll
            for (int wq = 0; wq < 4; ++wq) {
                const float phi = qw[(l * 4 + wq) * 3 + 0];
                const float th  = qw[(l * 4 + wq) * 3 + 1];
                const float om  = qw[(l * 4 + wq) * 3 + 2];
                float st_, ct_, sa, ca, sb, cb;
                __sincosf(0.5f * th, &st_, &ct_);
                __sincosf(0.5f * (phi + om), &sa, &ca);
                __sincosf(0.5f * (phi - om), &sb, &cb);
                const int mask = 8 >> wq;
                const bool bit = (ql & mask) != 0;
                const float dr  = ca * ct_;
                const float di  = (bit ? sa : -sa) * ct_;
                const float orr = (bit ? cb : -cb) * st_;
                const float oi  = -sb * st_;
                const float pr = __shfl_xor(ar, mask);
                const float pi = __shfl_xor(ai, mask);
                const float nr = dr * ar - di * ai + orr * pr - oi * pi;
                const float ni = dr * ai + di * ar + orr * pi + oi * pr;
                ar = nr; ai = ni;
            }
            const int r = (l % 3) + 1;
#pragma unroll
            for (int wq = 0; wq < 4; ++wq) {
                const int mc  = 8 >> wq;
                const int mt  = 8 >> ((wq + r) % 4);
                const int src = (ql & mc) ? (ql ^ mt) : ql;
                ar = __shfl(ar, grp | src);
                ai = __shfl(ai, grp | src);
            }
        }
        const float prob = ar * ar + ai * ai;
        float coeff = 0.0f;
#pragma unroll
        for (int wq = 0; wq < 4; ++wq) {
            const float sgn = (ql & (8 >> wq)) ? -1.0f : 1.0f;
            coeff = fmaf(sgn, Wo[wq], coeff);
        }
        float v = prob * coeff;
        v += __shfl_xor(v, 1);
        v += __shfl_xor(v, 2);
        v += __shfl_xor(v, 4);
        v += __shfl_xor(v, 8);
        if (ql == 0) out[blockIdx.x * SPB + s] = v + bo[0];
    }
}

extern "C" void kernel_launch(void* const* d_in, const int* in_sizes, int n_in,
                              void* d_out, int out_size, void* d_ws, size_t ws_size,
                              hipStream_t stream) {
    const float* x    = (const float*)d_in[0];
    const float* W_ih = (const float*)d_in[1];
    const float* W_hh = (const float*)d_in[2];
    const float* b_ih = (const float*)d_in[3];
    const float* b_hh = (const float*)d_in[4];
    const float* Wp   = (const float*)d_in[5];
    const float* bp   = (const float*)d_in[6];
    const float* qw   = (const float*)d_in[7];
    const float* Wo   = (const float*)d_in[8];
    const float* bo   = (const float*)d_in[9];
    float* out = (float*)d_out;

    const int B = in_sizes[0] / TSTEPS;
    hybrid_lstm_mfma13<<<B / SPB, THREADS, 0, stream>>>(x, W_ih, W_hh, b_ih, b_hh,
                                                        Wp, bp, qw, Wo, bo, out);
}

// Round 4
// 141.607 us; speedup vs baseline: 4.0575x; 1.0752x over previous
//
#include <hip/hip_runtime.h>

#define HID 50
#define TSTEPS 256
#define SPB 16              // samples per block (MFMA N)
#define NW 13               // waves per block, 1 M-tile (16 rows) each: 13*16 = 208 rows
#define THREADS (NW * 64)
#define XSTRIDE 257         // floats per sample in x_lds

#if __has_builtin(__builtin_amdgcn_exp2f)
#define EXP2(x) __builtin_amdgcn_exp2f(x)
#else
#define EXP2(x) exp2f(x)
#endif
#define L2E 1.44269504088896340736f

typedef __attribute__((ext_vector_type(8))) short short8;
typedef __attribute__((ext_vector_type(4))) float f32x4;

static __device__ __forceinline__ f32x4 MF(short8 a, short8 b, f32x4 c) {
    return __builtin_amdgcn_mfma_f32_16x16x32_bf16(a, b, c, 0, 0, 0);
}
static __device__ __forceinline__ unsigned short f2bf(float f) {   // RTNE
    unsigned u = __float_as_uint(f);
    return (unsigned short)((u + 0x7FFFu + ((u >> 16) & 1u)) >> 16);
}
static __device__ __forceinline__ float bf2f(unsigned short b) {
    return __uint_as_float(((unsigned)b) << 16);
}
// 1/(1 + 2^a)
static __device__ __forceinline__ float sig2(float a) {
    return __builtin_amdgcn_rcpf(1.0f + EXP2(a));
}
static __device__ __forceinline__ float fast_tanh(float x) {
    return 1.0f - 2.0f * sig2(2.0f * L2E * x);
}

__global__ __launch_bounds__(THREADS, 4) void hybrid_lstm_bcast(
    const float* __restrict__ x,      // [B,256,1]
    const float* __restrict__ W_ih,   // [200,1]
    const float* __restrict__ W_hh,   // [200,50]
    const float* __restrict__ b_ih,   // [200]
    const float* __restrict__ b_hh,   // [200]
    const float* __restrict__ Wp,     // [4,50]
    const float* __restrict__ bp,     // [4]
    const float* __restrict__ qw,     // [2,4,3]
    const float* __restrict__ Wo,     // [1,4]
    const float* __restrict__ bo,     // [1]
    float* __restrict__ out)          // [B,1]
{
    __shared__ __align__(16) float x_lds[SPB * XSTRIDE];
    // [buf][table*512 + chunk16B-per-lane]: tables: 0=hi k0..31, 1=hi k32..63, 2=lo k0..31, 3=lo k32..63
    // B-read for table T is exactly lane*16B within the table -> zero bank conflicts.
    __shared__ __align__(16) unsigned short h_tab[2][4 * 512];

    const int tid  = threadIdx.x;
    const int wid  = tid >> 6;        // tile index 0..12
    const int lane = tid & 63;
    const int qs   = lane & 15;       // sample / A-row-within-tile
    const int g2   = lane >> 4;       // K-group / C-row-group

    // ---------- prologue: zero h tables, stage x ----------
    {
        unsigned* hz = (unsigned*)&h_tab[0][0];
        for (int i = tid; i < 2 * 4 * 512 / 2; i += THREADS) hz[i] = 0u;
        const float* xg = x + (size_t)blockIdx.x * SPB * TSTEPS;
        for (int i = tid; i < SPB * TSTEPS; i += THREADS)
            x_lds[(i >> 8) * XSTRIDE + (i & 255)] = xg[i];
    }

    // ---------- A fragments (gate-scaled, hi/lo split) ----------
    // A-row: row' = 16*wid + qs -> unit uA = 4*wid + (qs>>2), gate q = qs&3 (i,f,g,o)
    // K-slot s holds unit un(s) = 4*(s%13) + s/13   (s = 13*(u&3) + (u>>2))
    // gate scale: i,f,o rows * -log2e ; g row * 2*log2e  (exp2-native gates)
    short8 Ahi[2], Alo[2];
    {
        const int uA   = 4 * wid + (qs >> 2);
        const bool vr  = (uA < HID);
        const int q    = qs & 3;
        const float sc = (q == 2) ? 2.0f * L2E : -L2E;
        const int orow = q * HID + (vr ? uA : 0);
#pragma unroll
        for (int kh = 0; kh < 2; ++kh) {
#pragma unroll
            for (int r = 0; r < 8; ++r) {
                const int s = kh * 32 + g2 * 8 + r;
                float v = 0.0f;
                if (vr && s < 52) {
                    const int un = 4 * (s % 13) + s / 13;
                    if (un < HID) v = sc * W_hh[orow * HID + un];
                }
                const unsigned short hi = f2bf(v);
                Ahi[kh][r] = (short)hi;
                Alo[kh][r] = (short)f2bf(v - bf2f(hi));
            }
        }
    }

    // per-lane gate constants: this lane owns unit u = 4*wid + g2 for sample qs
    const int u   = 4 * wid + g2;
    const bool uv = (u < HID);
    float wih4[4], bsum4[4];
#pragma unroll
    for (int reg = 0; reg < 4; ++reg) {
        const float sc = (reg == 2) ? 2.0f * L2E : -L2E;
        const int orow = reg * HID + (uv ? u : 0);
        wih4[reg]  = sc * W_ih[orow];
        bsum4[reg] = sc * (b_ih[orow] + b_hh[orow]);
    }

    // h write pointers: slot s_w = 13*g2 + wid; table = s_w>>5 (hi), +2 (lo)
    const int s_w  = 13 * g2 + wid;
    const int p17  = s_w & 31;
    const int widx = ((p17 >> 3) * 16 + qs) * 8 + (p17 & 7);
    unsigned short* const wp_hi = &h_tab[0][(s_w >> 5) * 512 + widx];

    __syncthreads();

    float cst = 0.0f;
    short8 bh0, bh1, bl0, bl1;
    float xt;

    auto loadB = [&](int buf, int t) {
        const unsigned short* bp_ = &h_tab[buf][0] + lane * 8;
        bh0 = *(const short8*)(bp_);
        bh1 = *(const short8*)(bp_ + 512);
        bl0 = *(const short8*)(bp_ + 1024);
        bl1 = *(const short8*)(bp_ + 1536);
        xt  = x_lds[qs * XSTRIDE + t];
    };

    loadB(1, 0);   // h(-1) = 0 from zeroed buf1

#pragma unroll 2
    for (int t = 0; t < TSTEPS; ++t) {
        // acc init carries exact fp32 (scaled) bias + W_ih*x_t
        f32x4 accA, accB;
#pragma unroll
        for (int reg = 0; reg < 4; ++reg) {
            accA[reg] = fmaf(wih4[reg], xt, bsum4[reg]);
            accB[reg] = 0.0f;
        }
        // 3-term split product as two independent 3-chains
        accA = MF(Ahi[0], bh0, accA);
        accB = MF(Ahi[0], bl0, accB);
        accA = MF(Ahi[1], bh1, accA);
        accB = MF(Ahi[1], bl1, accB);
        accA = MF(Alo[0], bh0, accA);
        accB = MF(Alo[1], bh1, accB);

        const float a0 = accA[0] + accB[0];
        const float a1 = accA[1] + accB[1];
        const float a2 = accA[2] + accB[2];
        const float a3 = accA[3] + accB[3];

        // a0,a1,a3 = -log2e * pre(i,f,o); a2 = 2log2e * pre(g)
        const float ig = sig2(a0);
        const float fg = sig2(a1);
        const float gg = 1.0f - 2.0f * sig2(a2);
        const float og = sig2(a3);
        cst = fmaf(fg, cst, ig * gg);
        const float h = og * fast_tanh(cst);

        if (uv) {
            const unsigned short hh = f2bf(h);
            unsigned short* wp = wp_hi + (t & 1) * (4 * 512);
            wp[0]    = hh;
            wp[1024] = f2bf(h - bf2f(hh));
        }
        __syncthreads();
        loadB(t & 1, t + 1);   // t=255 reads x_lds[...+256] (in-bounds, unused)
    }

    // ---------- epilogue: angles + 4-qubit circuit, 2 samples per wave (waves 0-7) ----------
    if (wid < 8 && lane < 32) {
        const int sm  = 2 * wid + (lane >> 4);
        const int ql  = lane & 15;
        const int grp = lane & 48;

        const unsigned short* t1 = &h_tab[1][0];   // h(255) lives in buf1
        float ang0 = bp[0], ang1 = bp[1], ang2 = bp[2], ang3 = bp[3];
#pragma unroll
        for (int k = 0; k < HID; ++k) {
            const int s   = 13 * (k & 3) + (k >> 2);
            const int p   = s & 31;
            const int idx = (s >> 5) * 512 + ((p >> 3) * 16 + sm) * 8 + (p & 7);
            const float hk = bf2f(t1[idx]) + bf2f(t1[idx + 1024]);
            ang0 = fmaf(Wp[0 * HID + k], hk, ang0);
            ang1 = fmaf(Wp[1 * HID + k], hk, ang1);
            ang2 = fmaf(Wp[2 * HID + k], hk, ang2);
            ang3 = fmaf(Wp[3 * HID + k], hk, ang3);
        }
        float ang[4];
        ang[0] = fast_tanh(ang0) * 1.57079632679489662f;
        ang[1] = fast_tanh(ang1) * 1.57079632679489662f;
        ang[2] = fast_tanh(ang2) * 1.57079632679489662f;
        ang[3] = fast_tanh(ang3) * 1.57079632679489662f;

        float ar = (ql == 0) ? 1.0f : 0.0f;
        float ai = 0.0f;

        // RX embedding
#pragma unroll
        for (int wq = 0; wq < 4; ++wq) {
            const int mask = 8 >> wq;
            float s_, c_;
            __sincosf(0.5f * ang[wq], &s_, &c_);
            const float pr = __shfl_xor(ar, mask);
            const float pi = __shfl_xor(ai, mask);
            const float nr = c_ * ar + s_ * pi;
            const float ni = c_ * ai - s_ * pr;
            ar = nr; ai = ni;
        }
        // StronglyEntanglingLayers
#pragma unroll
        for (int l = 0; l < 2; ++l) {
#pragma unroll
            for (int wq = 0; wq < 4; ++wq) {
                const float phi = qw[(l * 4 + wq) * 3 + 0];
                const float th  = qw[(l * 4 + wq) * 3 + 1];
                const float om  = qw[(l * 4 + wq) * 3 + 2];
                float st_, ct_, sa, ca, sb, cb;
                __sincosf(0.5f * th, &st_, &ct_);
                __sincosf(0.5f * (phi + om), &sa, &ca);
                __sincosf(0.5f * (phi - om), &sb, &cb);
                const int mask = 8 >> wq;
                const bool bit = (ql & mask) != 0;
                const float dr  = ca * ct_;
                const float di  = (bit ? sa : -sa) * ct_;
                const float orr = (bit ? cb : -cb) * st_;
                const float oi  = -sb * st_;
                const float pr = __shfl_xor(ar, mask);
                const float pi = __shfl_xor(ai, mask);
                const float nr = dr * ar - di * ai + orr * pr - oi * pi;
                const float ni = dr * ai + di * ar + orr * pi + oi * pr;
                ar = nr; ai = ni;
            }
            const int r = (l % 3) + 1;
#pragma unroll
            for (int wq = 0; wq < 4; ++wq) {
                const int mc  = 8 >> wq;
                const int mt  = 8 >> ((wq + r) % 4);
                const int src = (ql & mc) ? (ql ^ mt) : ql;
                ar = __shfl(ar, grp | src);
                ai = __shfl(ai, grp | src);
            }
        }
        const float prob = ar * ar + ai * ai;
        float coeff = 0.0f;
#pragma unroll
        for (int wq = 0; wq < 4; ++wq) {
            const float sgn = (ql & (8 >> wq)) ? -1.0f : 1.0f;
            coeff = fmaf(sgn, Wo[wq], coeff);
        }
        float v = prob * coeff;
        v += __shfl_xor(v, 1);
        v += __shfl_xor(v, 2);
        v += __shfl_xor(v, 4);
        v += __shfl_xor(v, 8);
        if (ql == 0) out[blockIdx.x * SPB + sm] = v + bo[0];
    }
}

extern "C" void kernel_launch(void* const* d_in, const int* in_sizes, int n_in,
                              void* d_out, int out_size, void* d_ws, size_t ws_size,
                              hipStream_t stream) {
    const float* x    = (const float*)d_in[0];
    const float* W_ih = (const float*)d_in[1];
    const float* W_hh = (const float*)d_in[2];
    const float* b_ih = (const float*)d_in[3];
    const float* b_hh = (const float*)d_in[4];
    const float* Wp   = (const float*)d_in[5];
    const float* bp   = (const float*)d_in[6];
    const float* qw   = (const float*)d_in[7];
    const float* Wo   = (const float*)d_in[8];
    const float* bo   = (const float*)d_in[9];
    float* out = (float*)d_out;

    const int B = in_sizes[0] / TSTEPS;
    hybrid_lstm_bcast<<<B / SPB, THREADS, 0, stream>>>(x, W_ih, W_hh, b_ih, b_hh,
                                                       Wp, bp, qw, Wo, bo, out);
}

// Round 5
// 109.059 us; speedup vs baseline: 5.2684x; 1.2984x over previous
//
#include <hip/hip_runtime.h>

#define HID 50
#define TSTEPS 256
#define SPB 16              // samples per block (MFMA N)
#define NW 13               // waves per block, 1 M-tile (16 rows) each: 13*16 = 208 rows
#define THREADS (NW * 64)
#define XSTRIDE 257         // floats per sample in x_lds

#if __has_builtin(__builtin_amdgcn_exp2f)
#define EXP2(x) __builtin_amdgcn_exp2f(x)
#else
#define EXP2(x) exp2f(x)
#endif
#define L2E 1.44269504088896340736f

typedef __attribute__((ext_vector_type(8))) _Float16 half8;
typedef __attribute__((ext_vector_type(4))) float f32x4;

static __device__ __forceinline__ f32x4 MF16(half8 a, half8 b, f32x4 c) {
    return __builtin_amdgcn_mfma_f32_16x16x32_f16(a, b, c, 0, 0, 0);
}
// 1/(1 + 2^a)
static __device__ __forceinline__ float sig2(float a) {
    return __builtin_amdgcn_rcpf(1.0f + EXP2(a));
}
static __device__ __forceinline__ float fast_tanh(float x) {
    return 1.0f - 2.0f * sig2(2.0f * L2E * x);
}

// slot permutation: unit u owned by wave w=u>>2, group g2=u&3
//   s(u) = 8*(u>>3) + 2*(u&3) + ((u>>2)&1)     (conflict-free h writes)
//   inverse: w = 2*(s>>3) + (s&1); un = 4*w + ((s>>1)&3)
static __device__ __forceinline__ int slot_of_unit(int u) {
    return 8 * (u >> 3) + 2 * (u & 3) + ((u >> 2) & 1);
}

__global__ __launch_bounds__(THREADS, 4) void hybrid_lstm_fp16(
    const float* __restrict__ x,      // [B,256,1]
    const float* __restrict__ W_ih,   // [200,1]
    const float* __restrict__ W_hh,   // [200,50]
    const float* __restrict__ b_ih,   // [200]
    const float* __restrict__ b_hh,   // [200]
    const float* __restrict__ Wp,     // [4,50]
    const float* __restrict__ bp,     // [4]
    const float* __restrict__ qw,     // [2,4,3]
    const float* __restrict__ Wo,     // [1,4]
    const float* __restrict__ bo,     // [1]
    float* __restrict__ out)          // [B,1]
{
    __shared__ __align__(16) float x_lds[SPB * XSTRIDE];
    // per buf: 2 chunk-tables of 512 fp16; table c holds K-slots 32c..32c+31.
    // entry(s,qs) = (s>>5)*512 + (((s&31)>>3)*16 + qs)*8 + ((s&31)&7)
    // B-read for chunk c = entries [lane*8 .. lane*8+8) of table c  (conflict-free)
    __shared__ __align__(16) _Float16 h_tab[2][1024];

    const int tid  = threadIdx.x;
    const int wid  = tid >> 6;        // tile index 0..12
    const int lane = tid & 63;
    const int qs   = lane & 15;       // sample / A-row-within-tile
    const int g2   = lane >> 4;       // K-group / C-row-group

    // ---------- prologue: zero h tables, stage x ----------
    {
        unsigned* hz = (unsigned*)&h_tab[0][0];
        for (int i = tid; i < 1024; i += THREADS) hz[i] = 0u;
        const float* xg = x + (size_t)blockIdx.x * SPB * TSTEPS;
        for (int i = tid; i < SPB * TSTEPS; i += THREADS)
            x_lds[(i >> 8) * XSTRIDE + (i & 255)] = xg[i];
    }

    // ---------- A fragments (gate-scaled, fp16) ----------
    // A-row: row' = 16*wid + qs -> unit uA = 4*wid + (qs>>2), gate q = qs&3 (i,f,g,o)
    // gate scale: i,f,o rows * -log2e ; g row * 2*log2e  (exp2-native gates)
    half8 Ah[2];
    {
        const int uA   = 4 * wid + (qs >> 2);
        const bool vr  = (uA < HID);
        const int q    = qs & 3;
        const float sc = (q == 2) ? 2.0f * L2E : -L2E;
        const int orow = q * HID + (vr ? uA : 0);
#pragma unroll
        for (int kh = 0; kh < 2; ++kh) {
#pragma unroll
            for (int r = 0; r < 8; ++r) {
                const int s  = kh * 32 + g2 * 8 + r;
                const int ws = 2 * (s >> 3) + (s & 1);
                const int un = 4 * ws + ((s >> 1) & 3);
                float v = 0.0f;
                if (vr && un < HID) v = sc * W_hh[orow * HID + un];
                Ah[kh][r] = (_Float16)v;
            }
        }
    }

    // per-lane gate constants: this lane owns unit u = 4*wid + g2 for sample qs
    const int u   = 4 * wid + g2;
    const bool uv = (u < HID);
    float wih4[4], bsum4[4];
#pragma unroll
    for (int reg = 0; reg < 4; ++reg) {
        const float sc = (reg == 2) ? 2.0f * L2E : -L2E;
        const int orow = reg * HID + (uv ? u : 0);
        wih4[reg]  = sc * W_ih[orow];
        bsum4[reg] = sc * (b_ih[orow] + b_hh[orow]);
    }

    // h write entry for this lane's unit
    const int s_w = slot_of_unit(uv ? u : 0);
    const int p_w = s_w & 31;
    _Float16* const wp0 = &h_tab[0][(s_w >> 5) * 512 + ((p_w >> 3) * 16 + qs) * 8 + (p_w & 7)];

    __syncthreads();

    float cst = 0.0f;
    half8 bh0, bh1;

    auto loadB = [&](int buf) {
        const _Float16* bp_ = &h_tab[buf][0] + lane * 8;
        bh0 = *(const half8*)(bp_);
        bh1 = *(const half8*)(bp_ + 512);
    };

    loadB(1);                                  // h(-1) = 0 from zeroed buf1
    float xt = x_lds[qs * XSTRIDE];            // t = 0

#pragma unroll 2
    for (int t = 0; t < TSTEPS; ++t) {
        // acc init carries exact fp32 (scaled) bias + W_ih*x_t
        f32x4 acc;
#pragma unroll
        for (int reg = 0; reg < 4; ++reg)
            acc[reg] = fmaf(wih4[reg], xt, bsum4[reg]);
        acc = MF16(Ah[0], bh0, acc);
        acc = MF16(Ah[1], bh1, acc);

        // acc0,1,3 = -log2e*pre(i,f,o); acc2 = 2log2e*pre(g)
        const float ig = sig2(acc[0]);
        const float fg = sig2(acc[1]);
        const float gg = 1.0f - 2.0f * sig2(acc[2]);
        const float og = sig2(acc[3]);
        cst = fmaf(fg, cst, ig * gg);
        const float h = og * fast_tanh(cst);

        const float xn = x_lds[qs * XSTRIDE + t + 1];   // prefetch (pad slot at t=255)
        if (uv) wp0[(t & 1) * 1024] = (_Float16)h;
        __syncthreads();
        loadB(t & 1);                                   // h(t) for next step
        xt = xn;
    }

    // ---------- epilogue: angles + 4-qubit circuit, 2 samples per wave (waves 0-7) ----------
    if (wid < 8 && lane < 32) {
        const int sm  = 2 * wid + (lane >> 4);
        const int ql  = lane & 15;
        const int grp = lane & 48;

        const _Float16* t1 = &h_tab[1][0];   // h(255) lives in buf1
        float ang0 = bp[0], ang1 = bp[1], ang2 = bp[2], ang3 = bp[3];
#pragma unroll
        for (int k = 0; k < HID; ++k) {
            const int s   = slot_of_unit(k);
            const int p   = s & 31;
            const int idx = (s >> 5) * 512 + ((p >> 3) * 16 + sm) * 8 + (p & 7);
            const float hk = (float)t1[idx];
            ang0 = fmaf(Wp[0 * HID + k], hk, ang0);
            ang1 = fmaf(Wp[1 * HID + k], hk, ang1);
            ang2 = fmaf(Wp[2 * HID + k], hk, ang2);
            ang3 = fmaf(Wp[3 * HID + k], hk, ang3);
        }
        float ang[4];
        ang[0] = fast_tanh(ang0) * 1.57079632679489662f;
        ang[1] = fast_tanh(ang1) * 1.57079632679489662f;
        ang[2] = fast_tanh(ang2) * 1.57079632679489662f;
        ang[3] = fast_tanh(ang3) * 1.57079632679489662f;

        float ar = (ql == 0) ? 1.0f : 0.0f;
        float ai = 0.0f;

        // RX embedding
#pragma unroll
        for (int wq = 0; wq < 4; ++wq) {
            const int mask = 8 >> wq;
            float s_, c_;
            __sincosf(0.5f * ang[wq], &s_, &c_);
            const float pr = __shfl_xor(ar, mask);
            const float pi = __shfl_xor(ai, mask);
            const float nr = c_ * ar + s_ * pi;
            const float ni = c_ * ai - s_ * pr;
            ar = nr; ai = ni;
        }
        // StronglyEntanglingLayers
#pragma unroll
        for (int l = 0; l < 2; ++l) {
#pragma unroll
            for (int wq = 0; wq < 4; ++wq) {
                const float phi = qw[(l * 4 + wq) * 3 + 0];
                const float th  = qw[(l * 4 + wq) * 3 + 1];
                const float om  = qw[(l * 4 + wq) * 3 + 2];
                float st_, ct_, sa, ca, sb, cb;
                __sincosf(0.5f * th, &st_, &ct_);
                __sincosf(0.5f * (phi + om), &sa, &ca);
                __sincosf(0.5f * (phi - om), &sb, &cb);
                const int mask = 8 >> wq;
                const bool bit = (ql & mask) != 0;
                const float dr  = ca * ct_;
                const float di  = (bit ? sa : -sa) * ct_;
                const float orr = (bit ? cb : -cb) * st_;
                const float oi  = -sb * st_;
                const float pr = __shfl_xor(ar, mask);
                const float pi = __shfl_xor(ai, mask);
                const float nr = dr * ar - di * ai + orr * pr - oi * pi;
                const float ni = dr * ai + di * ar + orr * pi + oi * pr;
                ar = nr; ai = ni;
            }
            const int r = (l % 3) + 1;
#pragma unroll
            for (int wq = 0; wq < 4; ++wq) {
                const int mc  = 8 >> wq;
                const int mt  = 8 >> ((wq + r) % 4);
                const int src = (ql & mc) ? (ql ^ mt) : ql;
                ar = __shfl(ar, grp | src);
                ai = __shfl(ai, grp | src);
            }
        }
        const float prob = ar * ar + ai * ai;
        float coeff = 0.0f;
#pragma unroll
        for (int wq = 0; wq < 4; ++wq) {
            const float sgn = (ql & (8 >> wq)) ? -1.0f : 1.0f;
            coeff = fmaf(sgn, Wo[wq], coeff);
        }
        float v = prob * coeff;
        v += __shfl_xor(v, 1);
        v += __shfl_xor(v, 2);
        v += __shfl_xor(v, 4);
        v += __shfl_xor(v, 8);
        if (ql == 0) out[blockIdx.x * SPB + sm] = v + bo[0];
    }
}

extern "C" void kernel_launch(void* const* d_in, const int* in_sizes, int n_in,
                              void* d_out, int out_size, void* d_ws, size_t ws_size,
                              hipStream_t stream) {
    const float* x    = (const float*)d_in[0];
    const float* W_ih = (const float*)d_in[1];
    const float* W_hh = (const float*)d_in[2];
    const float* b_ih = (const float*)d_in[3];
    const float* b_hh = (const float*)d_in[4];
    const float* Wp   = (const float*)d_in[5];
    const float* bp   = (const float*)d_in[6];
    const float* qw   = (const float*)d_in[7];
    const float* Wo   = (const float*)d_in[8];
    const float* bo   = (const float*)d_in[9];
    float* out = (float*)d_out;

    const int B = in_sizes[0] / TSTEPS;
    hybrid_lstm_fp16<<<B / SPB, THREADS, 0, stream>>>(x, W_ih, W_hh, b_ih, b_hh,
                                                      Wp, bp, qw, Wo, bo, out);
}